// Round 5
// baseline (1211.985 us; speedup 1.0000x reference)
//
#include <hip/hip_runtime.h>
#include <math.h>

#define SEQ_LEN   720
#define IN_LEN    360
#define PRED_LEN  336
#define CHANNELS  862
#define RANK      32
#define BATCH     256

// ws layout (float offsets)
#define WS_WP    0        // Wp  [360][32] = DCT^T@A folded, incl. 1/(360*sqrt2)
#define WS_VT    11520    // Vt  [336][32] = (B @ M_IDCT)^T
#define WS_CVEC  22272    // cvec[336]     = b @ M_IDCT

// LDS float-offset map (total 40464 floats = 161,856 B <= 163,840)
//   EX  [68][432] at 0      (exchange; W[360][32] overlays [0,11520) during phase 1)
//   V   [336][32] at 29376
//   cvec[336]     at 40128
#define LDSF_EX   0
#define LDSF_V    29376
#define LDSF_CV   40128
#define LDSF_TOT  40464

// ---------------- single prep kernel (89 blocks) -----------------------------
__global__ __launch_bounds__(256) void k_prep(const float* __restrict__ A,
                                              const float* __restrict__ B,
                                              const float* __restrict__ bias,
                                              float* __restrict__ Wp,
                                              float* __restrict__ Vt,
                                              float* __restrict__ cvec) {
    __shared__ float sbuf[IN_LEN * RANK];            // 46080 B
    int blk = blockIdx.x;
    if (blk < 45) {
        for (int i = threadIdx.x; i < IN_LEN * RANK; i += 256) sbuf[i] = A[i];
        __syncthreads();
        int idx = blk * 256 + threadIdx.x;           // 45*256 == 11520
        int n = idx >> 5, r = idx & 31;
        int step = 2 * n + 1, m = 0;                 // k*(2n+1) mod 1440
        float sum = 0.f;
        for (int k = 0; k < IN_LEN; ++k) {
            float coef = (k == 0) ? 0.05270462766947299f    // 1/sqrt(360)
                                  : 0.07453559924999299f;   // 2/sqrt(720)
            float d = coef * cospif((float)m * (1.0f / 720.0f));
            sum = fmaf(d, sbuf[k * RANK + r], sum);
            m += step; if (m >= 1440) m -= 1440;
        }
        Wp[idx] = sum * 0.0019641855032960957f;      // (1/sqrt2)/360
    } else if (blk < 87) {
        for (int i = threadIdx.x; i < PRED_LEN * RANK; i += 256) {
            int r = i / PRED_LEN, k = i - r * PRED_LEN;
            sbuf[k * RANK + r] = B[i];               // B transposed -> [k][r]
        }
        __syncthreads();
        int idx = (blk - 45) * 256 + threadIdx.x;    // 42*256 == 10752
        int n = idx >> 5, r = idx & 31;
        int step = 2 * n + 1, m = 0;                 // k*(2n+1) mod 1344
        float sum = 0.f;
        for (int k = 0; k < PRED_LEN; ++k) {
            float mk = cospif((float)m * (1.0f / 672.0f));
            if (k == 0) mk *= 0.5f;
            sum = fmaf(mk, sbuf[k * RANK + r], sum);
            m += step; if (m >= 1344) m -= 1344;
        }
        Vt[idx] = sum * (1.0f / 336.0f);
    } else {
        int n = (blk - 87) * 256 + threadIdx.x;
        if (n < PRED_LEN) {
            int step = 2 * n + 1, m = 0;
            float sum = 0.f;
            for (int k = 0; k < PRED_LEN; ++k) {
                float mk = cospif((float)m * (1.0f / 672.0f));
                if (k == 0) mk *= 0.5f;
                sum = fmaf(mk, bias[k], sum);
                m += step; if (m >= 1344) m -= 1344;
            }
            cvec[n] = sum * (1.0f / 336.0f);
        }
    }
}

__device__ __forceinline__ unsigned f2bf(float f) {   // rne fp32 -> bf16 (in low 16)
    unsigned u = __float_as_uint(f);
    return (u + 0x7FFFu + ((u >> 16) & 1u)) >> 16;
}

// ---------------- fused main kernel ------------------------------------------
// 512 threads = 8 waves per block, 1 block per batch (grid 256 -> 1 block/CU).
// Wave-group 0 (tid<256): t-rows 0-179; group 1: rows 180-359. Partial acc
// exchanged via LDS (bf16 packed, SoA conflict-free). Both groups finalize,
// then phase 2 n-split: group 0 -> n 0-167, group 1 -> n 168-335.
// 4 channels/thread (216 active threads of 256 per group).
__global__ __launch_bounds__(512, 2) void k_main(const float* __restrict__ x,
                                                 const float* __restrict__ A,
                                                 const float* __restrict__ Wp,
                                                 const float* __restrict__ Vt,
                                                 const float* __restrict__ cvec,
                                                 float* __restrict__ out) {
    __shared__ float ldsf[LDSF_TOT];                 // 161,856 B
    const int tid = threadIdx.x;
    const int b = blockIdx.x;
    const int grp = tid >> 8;                        // 0 | 1
    const int i = tid & 255;
    const bool active = (i < 216);
    int c0 = 4 * i; if (c0 > CHANNELS - 4) c0 = CHANNELS - 4;   // clamp-duplicate tail

    // ---- stage W (overlay on EX), V, cvec ----
    {
        float4* dw = (float4*)ldsf;
        const float4* sw = (const float4*)Wp;
        for (int idx = tid; idx < IN_LEN * RANK / 4; idx += 512) dw[idx] = sw[idx];
        float4* dv = (float4*)(ldsf + LDSF_V);
        const float4* sv = (const float4*)Vt;
        for (int idx = tid; idx < PRED_LEN * RANK / 4; idx += 512) dv[idx] = sv[idx];
        for (int idx = tid; idx < PRED_LEN; idx += 512) ldsf[LDSF_CV + idx] = cvec[idx];
    }
    __syncthreads();

    float acc0[RANK], acc1[RANK], acc2[RANK], acc3[RANK];
    #pragma unroll
    for (int r = 0; r < RANK; ++r) { acc0[r]=0.f; acc1[r]=0.f; acc2[r]=0.f; acc3[r]=0.f; }
    float S0 = 0.f, S1 = 0.f, S2 = 0.f, S3 = 0.f;

    // ---- phase 1: partial t over this group's 180 rows ----
    if (active) {
        const float* xbase = x + (size_t)b * (SEQ_LEN * CHANNELS)
                               + (size_t)grp * (IN_LEN * CHANNELS) + c0;
        #define LR2(row, half) (*(const float2*)(xbase + (size_t)(row) * CHANNELS + 2 * (half)))
        float2 cur[16], nxt[16];
        #pragma unroll
        for (int j = 0; j < 8; ++j) { cur[2*j] = LR2(j, 0); cur[2*j+1] = LR2(j, 1); }

        for (int g = 0; g < 45; ++g) {               // 45 groups x 4 rows = 180
            const int nrb = (g < 44) ? 8 * (g + 1) : 0;
            #pragma unroll
            for (int j = 0; j < 8; ++j) { nxt[2*j] = LR2(nrb + j, 0); nxt[2*j+1] = LR2(nrb + j, 1); }

            #pragma unroll
            for (int k = 0; k < 4; ++k) {            // local n = 4g+k
                float2 e0 = cur[4*k+0], e1 = cur[4*k+1];
                float2 o0 = cur[4*k+2], o1 = cur[4*k+3];
                float p0 = e0.x + o0.x, p1 = e0.y + o0.y;
                float p2 = e1.x + o1.x, p3 = e1.y + o1.y;
                S0 += p0; S1 += p1; S2 += p2; S3 += p3;
                const float4* wrow = (const float4*)ldsf + (grp * 180 + 4 * g + k) * 8;
                #pragma unroll
                for (int q = 0; q < 8; ++q) {
                    float4 wv = wrow[q];
                    acc0[4*q+0] = fmaf(p0, wv.x, acc0[4*q+0]);
                    acc1[4*q+0] = fmaf(p1, wv.x, acc1[4*q+0]);
                    acc2[4*q+0] = fmaf(p2, wv.x, acc2[4*q+0]);
                    acc3[4*q+0] = fmaf(p3, wv.x, acc3[4*q+0]);
                    acc0[4*q+1] = fmaf(p0, wv.y, acc0[4*q+1]);
                    acc1[4*q+1] = fmaf(p1, wv.y, acc1[4*q+1]);
                    acc2[4*q+1] = fmaf(p2, wv.y, acc2[4*q+1]);
                    acc3[4*q+1] = fmaf(p3, wv.y, acc3[4*q+1]);
                    acc0[4*q+2] = fmaf(p0, wv.z, acc0[4*q+2]);
                    acc1[4*q+2] = fmaf(p1, wv.z, acc1[4*q+2]);
                    acc2[4*q+2] = fmaf(p2, wv.z, acc2[4*q+2]);
                    acc3[4*q+2] = fmaf(p3, wv.z, acc3[4*q+2]);
                    acc0[4*q+3] = fmaf(p0, wv.w, acc0[4*q+3]);
                    acc1[4*q+3] = fmaf(p1, wv.w, acc1[4*q+3]);
                    acc2[4*q+3] = fmaf(p2, wv.w, acc2[4*q+3]);
                    acc3[4*q+3] = fmaf(p3, wv.w, acc3[4*q+3]);
                }
            }
            #pragma unroll
            for (int j = 0; j < 16; ++j) cur[j] = nxt[j];
        }
        #undef LR2
    }
    __syncthreads();                                 // all W reads done -> EX may overlay

    // ---- write partials (bf16-packed acc + fp32 S), SoA [68][432] ----
    if (active) {
        const int slot = grp * 216 + i;
        #pragma unroll
        for (int u = 0; u < 16; ++u)
            ldsf[(u)      * 432 + slot] = __uint_as_float(f2bf(acc0[2*u]) | (f2bf(acc0[2*u+1]) << 16));
        #pragma unroll
        for (int u = 0; u < 16; ++u)
            ldsf[(16 + u) * 432 + slot] = __uint_as_float(f2bf(acc1[2*u]) | (f2bf(acc1[2*u+1]) << 16));
        #pragma unroll
        for (int u = 0; u < 16; ++u)
            ldsf[(32 + u) * 432 + slot] = __uint_as_float(f2bf(acc2[2*u]) | (f2bf(acc2[2*u+1]) << 16));
        #pragma unroll
        for (int u = 0; u < 16; ++u)
            ldsf[(48 + u) * 432 + slot] = __uint_as_float(f2bf(acc3[2*u]) | (f2bf(acc3[2*u+1]) << 16));
        ldsf[64 * 432 + slot] = S0;
        ldsf[65 * 432 + slot] = S1;
        ldsf[66 * 432 + slot] = S2;
        ldsf[67 * 432 + slot] = S3;
    }
    __syncthreads();

    if (active) {
        // ---- combine with partner group's partials ----
        const int pslot = (1 - grp) * 216 + i;
        #pragma unroll
        for (int u = 0; u < 16; ++u) {
            unsigned w = __float_as_uint(ldsf[(u)      * 432 + pslot]);
            acc0[2*u]   += __uint_as_float(w << 16);
            acc0[2*u+1] += __uint_as_float(w & 0xFFFF0000u);
        }
        #pragma unroll
        for (int u = 0; u < 16; ++u) {
            unsigned w = __float_as_uint(ldsf[(16 + u) * 432 + pslot]);
            acc1[2*u]   += __uint_as_float(w << 16);
            acc1[2*u+1] += __uint_as_float(w & 0xFFFF0000u);
        }
        #pragma unroll
        for (int u = 0; u < 16; ++u) {
            unsigned w = __float_as_uint(ldsf[(32 + u) * 432 + pslot]);
            acc2[2*u]   += __uint_as_float(w << 16);
            acc2[2*u+1] += __uint_as_float(w & 0xFFFF0000u);
        }
        #pragma unroll
        for (int u = 0; u < 16; ++u) {
            unsigned w = __float_as_uint(ldsf[(48 + u) * 432 + pslot]);
            acc3[2*u]   += __uint_as_float(w << 16);
            acc3[2*u+1] += __uint_as_float(w & 0xFFFF0000u);
        }
        S0 += ldsf[64 * 432 + pslot];
        S1 += ldsf[65 * 432 + pslot];
        S2 += ldsf[66 * 432 + pslot];
        S3 += ldsf[67 * 432 + pslot];

        // ---- finalize: csw[r] = A[0][r]/sqrt(720); t -= (S/360)*csw ----
        const float k360 = (1.0f / 360.0f) * 0.037267799624996496f;
        float g0 = -S0 * k360, g1 = -S1 * k360, g2 = -S2 * k360, g3 = -S3 * k360;
        #pragma unroll
        for (int q = 0; q < 8; ++q) {
            float4 a4 = ((const float4*)A)[q];       // A[0][0..31], uniform, L2-hot
            acc0[4*q+0] = fmaf(g0, a4.x, acc0[4*q+0]);
            acc1[4*q+0] = fmaf(g1, a4.x, acc1[4*q+0]);
            acc2[4*q+0] = fmaf(g2, a4.x, acc2[4*q+0]);
            acc3[4*q+0] = fmaf(g3, a4.x, acc3[4*q+0]);
            acc0[4*q+1] = fmaf(g0, a4.y, acc0[4*q+1]);
            acc1[4*q+1] = fmaf(g1, a4.y, acc1[4*q+1]);
            acc2[4*q+1] = fmaf(g2, a4.y, acc2[4*q+1]);
            acc3[4*q+1] = fmaf(g3, a4.y, acc3[4*q+1]);
            acc0[4*q+2] = fmaf(g0, a4.z, acc0[4*q+2]);
            acc1[4*q+2] = fmaf(g1, a4.z, acc1[4*q+2]);
            acc2[4*q+2] = fmaf(g2, a4.z, acc2[4*q+2]);
            acc3[4*q+2] = fmaf(g3, a4.z, acc3[4*q+2]);
            acc0[4*q+3] = fmaf(g0, a4.w, acc0[4*q+3]);
            acc1[4*q+3] = fmaf(g1, a4.w, acc1[4*q+3]);
            acc2[4*q+3] = fmaf(g2, a4.w, acc2[4*q+3]);
            acc3[4*q+3] = fmaf(g3, a4.w, acc3[4*q+3]);
        }
        const float mean0 = S0 * (1.0f / 720.0f);
        const float mean1 = S1 * (1.0f / 720.0f);
        const float mean2 = S2 * (1.0f / 720.0f);
        const float mean3 = S3 * (1.0f / 720.0f);

        // ---- phase 2: this group's 168 output rows ----
        float* op = out + (size_t)b * (PRED_LEN * CHANNELS)
                        + (size_t)(grp * 168) * CHANNELS + c0;
        for (int nl = 0; nl < 168; ++nl) {
            const int n = grp * 168 + nl;
            const float4* vrow = (const float4*)(ldsf + LDSF_V) + n * 8;
            float o0a=0.f,o0b=0.f,o0c=0.f,o0d=0.f;
            float o1a=0.f,o1b=0.f,o1c=0.f,o1d=0.f;
            float o2a=0.f,o2b=0.f,o2c=0.f,o2d=0.f;
            float o3a=0.f,o3b=0.f,o3c=0.f,o3d=0.f;
            #pragma unroll
            for (int q = 0; q < 8; ++q) {
                float4 vv = vrow[q];
                o0a = fmaf(acc0[4*q+0], vv.x, o0a);
                o1a = fmaf(acc1[4*q+0], vv.x, o1a);
                o2a = fmaf(acc2[4*q+0], vv.x, o2a);
                o3a = fmaf(acc3[4*q+0], vv.x, o3a);
                o0b = fmaf(acc0[4*q+1], vv.y, o0b);
                o1b = fmaf(acc1[4*q+1], vv.y, o1b);
                o2b = fmaf(acc2[4*q+1], vv.y, o2b);
                o3b = fmaf(acc3[4*q+1], vv.y, o3b);
                o0c = fmaf(acc0[4*q+2], vv.z, o0c);
                o1c = fmaf(acc1[4*q+2], vv.z, o1c);
                o2c = fmaf(acc2[4*q+2], vv.z, o2c);
                o3c = fmaf(acc3[4*q+2], vv.z, o3c);
                o0d = fmaf(acc0[4*q+3], vv.w, o0d);
                o1d = fmaf(acc1[4*q+3], vv.w, o1d);
                o2d = fmaf(acc2[4*q+3], vv.w, o2d);
                o3d = fmaf(acc3[4*q+3], vv.w, o3d);
            }
            float cvn = ldsf[LDSF_CV + n];
            float2 w0, w1;
            w0.x = (o0a + o0b) + (o0c + o0d) + cvn + mean0;
            w0.y = (o1a + o1b) + (o1c + o1d) + cvn + mean1;
            w1.x = (o2a + o2b) + (o2c + o2d) + cvn + mean2;
            w1.y = (o3a + o3b) + (o3c + o3d) + cvn + mean3;
            *(float2*)(op)     = w0;
            *(float2*)(op + 2) = w1;
            op += CHANNELS;
        }
    }
}

// ---------------- launcher ---------------------------------------------------

extern "C" void kernel_launch(void* const* d_in, const int* in_sizes, int n_in,
                              void* d_out, int out_size, void* d_ws, size_t ws_size,
                              hipStream_t stream) {
    (void)in_sizes; (void)n_in; (void)out_size; (void)ws_size;
    const float* x    = (const float*)d_in[0];
    const float* A    = (const float*)d_in[1];
    const float* B    = (const float*)d_in[2];
    const float* bias = (const float*)d_in[3];
    float* out = (float*)d_out;
    float* ws  = (float*)d_ws;

    float* Wp   = ws + WS_WP;
    float* Vt   = ws + WS_VT;
    float* cvec = ws + WS_CVEC;

    k_prep<<<dim3(89), dim3(256), 0, stream>>>(A, B, bias, Wp, Vt, cvec);
    k_main<<<dim3(BATCH), dim3(512), 0, stream>>>(x, A, Wp, Vt, cvec, out);
}